// Round 7
// baseline (69.350 us; speedup 1.0000x reference)
//
#include <hip/hip_runtime.h>
#include <hip/hip_bf16.h>
#include <math.h>

#define N_ 256
#define C_ 100
#define D_ 512
#define LOG2E 1.44269504088896f

// ---- ws layout (float indices) ----
#define WS_GX  0         // [256][256] raw X.X gram; ONLY upper triangle (m>=b) valid
#define WS_GTP 65536     // [25][256][4] X.P gram PRE-SCALED by sp[c] (class-quad-major)
#define WS_RN  91136     // [256] scales 3/||x_row|| (bf16-gram diag, validated R1-R6)

typedef __attribute__((ext_vector_type(8))) short short8;
typedef __attribute__((ext_vector_type(4))) float floatx4;

__device__ inline float waveReduceSum(float v) {
    #pragma unroll
    for (int off = 32; off > 0; off >>= 1) v += __shfl_xor(v, off, 64);
    return v;
}
__device__ inline float clip1(float x) { return fminf(fmaxf(x, -1.0f), 1.0f); }

__device__ inline short8 cvt8(float4 a, float4 b) {
    union { __hip_bfloat16 h[8]; short8 s; } u;
    u.h[0] = __float2bfloat16(a.x); u.h[1] = __float2bfloat16(a.y);
    u.h[2] = __float2bfloat16(a.z); u.h[3] = __float2bfloat16(a.w);
    u.h[4] = __float2bfloat16(b.x); u.h[5] = __float2bfloat16(b.y);
    u.h[6] = __float2bfloat16(b.z); u.h[7] = __float2bfloat16(b.w);
    return u.s;
}

// K1: needed-tiles Gram, 16-way K-split (1024 thr: wave w owns k-chunk w*32,
// chain = ONE MFMA). Tiles:
//   [0,136):   upper-tri X.X (tm<=tn) -> Gx raw (+ rn on diag tiles)
//   [136,248): X.P tm=u/7 tn=u%7     -> GTP[c>>2][row][c&3] = raw * sp[c]
// P-col norms computed IN-BLOCK during the B-load (f32 squares + quad-shfl +
// LDS fold) -> sp folded at store time; P.P diag tiles deleted; K2 needs no
// proxy scales at all. Math per element identical to validated R5/R6 path,
// only K-sum association (16-way) and the sp multiply position differ.
__global__ __launch_bounds__(1024)
void gemm_kernel(const float* __restrict__ X, const float* __restrict__ P,
                 float* __restrict__ ws) {
    float* Gx  = ws + WS_GX;
    float* GTP = ws + WS_GTP;
    float* rn  = ws + WS_RN;
    __shared__ floatx4 accl[15][64];
    __shared__ float normp[16][16];
    int tile = blockIdx.x;
    int t = threadIdx.x, w = t >> 6, lane = t & 63;
    int r = lane & 15, quad = lane >> 4;
    const float *arow, *brow;
    int tm, tn, mode;
    if (tile < 136) {                        // upper-tri X.X
        mode = 0;
        int u = tile; tm = 0;
        while (u >= 16 - tm) { u -= 16 - tm; ++tm; }   // uniform scalar decode
        tn = tm + u;
        arow = X + (size_t)(tm * 16 + r) * D_;
        brow = X + (size_t)(tn * 16 + r) * D_;
    } else {                                 // X.P
        int u = tile - 136; mode = 1; tm = u / 7; tn = u - tm * 7;
        int pb = tn * 16 + r; if (pb >= C_) pb = 0;    // clamped lanes not stored
        arow = X + (size_t)(tm * 16 + r) * D_;
        brow = P + (size_t)pb * D_;
    }
    int k0 = w * 32;
    const float4* ap = (const float4*)(arow + k0 + quad * 8);
    const float4* bp = (const float4*)(brow + k0 + quad * 8);
    float4 a0 = ap[0], a1v = ap[1];
    float4 b0 = bp[0], b1v = bp[1];
    short8 av = cvt8(a0, a1v);
    short8 bv = cvt8(b0, b1v);
    floatx4 acc = {0.0f, 0.0f, 0.0f, 0.0f};
    acc = __builtin_amdgcn_mfma_f32_16x16x32_bf16(av, bv, acc, 0, 0, 0);
    // B-col-norm partial (consumed only in mode 1)
    float s8 = b0.x*b0.x + b0.y*b0.y + b0.z*b0.z + b0.w*b0.w
             + b1v.x*b1v.x + b1v.y*b1v.y + b1v.z*b1v.z + b1v.w*b1v.w;
    s8 += __shfl_xor(s8, 16, 64);
    s8 += __shfl_xor(s8, 32, 64);            // per-r: this wave's k-chunk col-norm
    if (quad == 0) normp[w][r] = s8;
    if (w) accl[w - 1][lane] = acc;
    __syncthreads();
    if (w == 0) {
        #pragma unroll
        for (int i = 0; i < 15; ++i) acc += accl[i][lane];
        int row0 = tm * 16 + quad * 4, col = tn * 16 + r;
        if (mode == 0) {
            #pragma unroll
            for (int i = 0; i < 4; ++i) Gx[(row0 + i) * 256 + col] = acc[i];
            if (tm == tn && (r >> 2) == quad)
                rn[tm * 16 + r] = 3.0f * rsqrtf(fmaxf(acc[r & 3], 1e-24f));
        } else {
            float cn = 0.0f;
            #pragma unroll
            for (int i = 0; i < 16; ++i) cn += normp[i][r];
            float spc = 3.0f * rsqrtf(fmaxf(cn, 1e-24f));
            int c = col;
            if (c < C_) {
                #pragma unroll
                for (int i = 0; i < 4; ++i)
                    GTP[(c >> 2) * 1024 + (row0 + i) * 4 + (c & 3)] = acc[i] * spc;
            }
        }
    }
}

// K2: 256 blocks x 1024 thr; slot = 4 lanes (m = t>>2, p = t&3): pair (b,m)
// for m>b with T-diff; m==b = diag = real loss (lam=1 exact reduction,
// validated R2-R6). Changes this round:
//  - GTP arrives pre-scaled by sp[c]: no sps loads, no wbufS, one less mul
//    per class; ip* = u*scale (association change only).
//  - t1/t2-dependent row-m gathers hoisted to entry (overlap wbuf staging).
//  - 4 accumulators (sm0..3) restore a 7-deep (not 28-deep) add chain.
// Barrier-free front end + tail hist/epilogue as validated R6.
__global__ __launch_bounds__(1024)
void pair_kernel(const float* __restrict__ ws, const int* __restrict__ T,
                 float* __restrict__ out) {
    const float* Gx   = ws + WS_GX;
    const float4* G4  = (const float4*)(ws + WS_GTP);
    const float* GTPf = ws + WS_GTP;
    const float* rn   = ws + WS_RN;
    __shared__ __attribute__((aligned(16))) float wbufA[16][104];
    __shared__ int hist[C_];
    __shared__ float red[16];

    int t = threadIdx.x, w = t >> 6, lane = t & 63;
    int b = blockIdx.x;
    int m = t >> 2, p = t & 3;

    // ---- early independent loads (no barrier ahead of the math) ----
    int t1 = T[b];                         // uniform
    int t2 = T[m];                         // per-slot
    float s1 = rn[b], sc2 = rn[m];
    float graw = 0.0f;
    if (m >= b) graw = Gx[b * 256 + m];    // lower tri = poison, never loaded
    float4 a2r[7];
    #pragma unroll
    for (int k = 0; k < 7; ++k) {
        int q = p + 4 * k;
        a2r[k] = (float4){0.f, 0.f, 0.f, 0.f};
        if (q < 25 && m >= b) a2r[k] = G4[q * 256 + m];
    }
    // t-dependent gathers issued as early as possible (2nd round trip)
    float u2t1 = GTPf[(t1 >> 2) * 1024 + m * 4 + (t1 & 3)];
    float u2t2 = GTPf[(t2 >> 2) * 1024 + m * 4 + (t2 & 3)];
    int Tt = (t < 256) ? T[t] : 0;         // hist feed
    if (t < C_) hist[t] = 0;
    // per-wave staging of pre-scaled GTP row b (same-wave write->read, no barrier)
    if (lane < 25) {
        float4 av = G4[lane * 256 + b];
        *(float4*)&wbufA[w][lane * 4] = av;
    }

    // ---- pair math ----
    bool diag = (m == b);
    bool act = diag || ((m > b) && (t2 != t1));
    float contrib = 0.0f;
    if (act) {
        float ip11 = wbufA[w][t1] * s1, ip12 = wbufA[w][t2] * s1;
        float ip21 = u2t1 * sc2,        ip22 = u2t2 * sc2;
        float X1P1 = clip1(ip11), X1P2 = clip1(ip12);
        float X2P1 = clip1(ip21), X2P2 = clip1(ip22);
        float num = X2P2 - X2P1;
        float den = num + X1P1 - X1P2;
        float lam = fminf(fmaxf(num / den, 0.3f), 0.7f);
        if (diag) lam = 1.0f;              // exact real-loss reduction
        float oml = 1.0f - lam;
        float g = graw * s1 * sc2;
        float wn2 = 9.0f * (lam * lam + oml * oml) + 2.0f * lam * oml * g;
        float ss2 = 6.0f * rsqrtf(fmaxf(wn2, 1e-24f));
        float la = ss2 * lam * s1 * LOG2E, lb = ss2 * oml * sc2 * LOG2E;
        float sm0 = 0.0f, sm1 = 0.0f, sm2 = 0.0f, sm3 = 0.0f;
        #pragma unroll
        for (int k = 0; k < 7; ++k) {
            int q = p + 4 * k;
            if (q < 25) {
                float4 a1 = *(const float4*)&wbufA[w][q * 4];
                float4 a2 = a2r[k];
                sm0 += exp2f(la * a1.x + lb * a2.x);
                sm1 += exp2f(la * a1.y + lb * a2.y);
                sm2 += exp2f(la * a1.z + lb * a2.z);
                sm3 += exp2f(la * a1.w + lb * a2.w);
            }
        }
        float sm = (sm0 + sm1) + (sm2 + sm3);
        sm += __shfl_xor(sm, 1, 64);       // act is slot-uniform -> partners valid
        sm += __shfl_xor(sm, 2, 64);
        if (p == 0) {
            float LSE = logf(sm);
            float ec1 = ss2 * (lam * ip11 + oml * ip21);
            float ec2 = ss2 * (lam * ip12 + oml * ip22);
            contrib = LSE - lam * ec1 - oml * ec2;
        }
    }
    float rsum = waveReduceSum(contrib);
    if (lane == 0) red[w] = rsum;
    __syncthreads();                       // bar1: hist zero + red complete
    if (t < 256) atomicAdd(&hist[Tt], 1);
    __syncthreads();                       // bar2: hist complete
    if (w == 0) {
        float same;
        { float n = (float)hist[lane]; same = 0.5f * n * (n - 1.0f); }
        if (lane + 64 < C_) { float n = (float)hist[lane + 64]; same += 0.5f * n * (n - 1.0f); }
        float bs = (lane < 16) ? red[lane] : 0.0f;
        same = waveReduceSum(same);
        bs = waveReduceSum(bs);
        if (lane == 0) atomicAdd(out, bs / (32896.0f - same));
    }
}

extern "C" void kernel_launch(void* const* d_in, const int* in_sizes, int n_in,
                              void* d_out, int out_size, void* d_ws, size_t ws_size,
                              hipStream_t stream) {
    const float* X = (const float*)d_in[0];   // (256, 512) f32
    const float* P = (const float*)d_in[1];   // (100, 512) f32
    const int*   T = (const int*)d_in[2];     // (256,) i32
    // d_in[3] = indices, unused
    float* ws = (float*)d_ws;                 // ~366 KB used
    float* out = (float*)d_out;

    gemm_kernel<<<248, 1024, 0, stream>>>(X, P, ws);
    pair_kernel<<<N_, 1024, 0, stream>>>(ws, T, out);
}